// Round 4
// baseline (389.283 us; speedup 1.0000x reference)
//
#include <hip/hip_runtime.h>

#define N 8192
#define DIM 128

typedef float f32x4 __attribute__((ext_vector_type(4)));

// ---------------------------------------------------------------------------
// Pass 0: encoder MLP. 128 -> 64 -> 32 -> 16 -> 16, relu on first three.
// Unchanged from Round 3 (measured-good): one thread per row, 64-thread
// blocks, weights in LDS, padded LDS columns for activations, plus the
// transposed copy z_T[16][N] via 16 coalesced scalar stores.
// ---------------------------------------------------------------------------
__global__ __launch_bounds__(64) void encoder_kernel(
    const float* __restrict__ x,
    const float* __restrict__ W1, const float* __restrict__ b1,
    const float* __restrict__ W2, const float* __restrict__ b2,
    const float* __restrict__ W3, const float* __restrict__ b3,
    const float* __restrict__ W4, const float* __restrict__ b4,
    float* __restrict__ z, float* __restrict__ zT, float* __restrict__ sqout)
{
    __shared__ float sW2[64 * 32];
    __shared__ float sW3[32 * 16];
    __shared__ float sW4[16 * 16];
    __shared__ float sb1[64];
    __shared__ float sb2[32];
    __shared__ float sb3[16];
    __shared__ float sb4[16];
    __shared__ float sW1[128 * 64];   // reused for h2/h3 staging after layer 1
    __shared__ float sh1[64 * 65];    // stride 65: bank = (t + k) % 32, conflict-free

    int t = threadIdx.x;
    float* sh2 = sW1;                 // 64*33 = 2112 floats
    float* sh3 = sW1 + 2112;          // 64*17 = 1088 floats  (3200 <= 8192, fits)

    for (int idx = t; idx < 128 * 64; idx += 64) sW1[idx] = W1[idx];
    for (int idx = t; idx < 64 * 32; idx += 64) sW2[idx] = W2[idx];
    for (int idx = t; idx < 32 * 16; idx += 64) sW3[idx] = W3[idx];
    for (int idx = t; idx < 16 * 16; idx += 64) sW4[idx] = W4[idx];
    sb1[t] = b1[t];
    if (t < 32) sb2[t] = b2[t];
    if (t < 16) { sb3[t] = b3[t]; sb4[t] = b4[t]; }
    __syncthreads();

    int row = blockIdx.x * 64 + t;
    const float4* xr = (const float4*)(x + (size_t)row * DIM);

    // ---- layer 1: 128 -> 64 ----
    float h1[64];
    #pragma unroll
    for (int k = 0; k < 64; ++k) h1[k] = sb1[k];
    for (int j4 = 0; j4 < 32; ++j4) {
        float4 xv = xr[j4];
        const float* w0 = &sW1[(j4 * 4 + 0) * 64];
        const float* w1 = &sW1[(j4 * 4 + 1) * 64];
        const float* w2 = &sW1[(j4 * 4 + 2) * 64];
        const float* w3 = &sW1[(j4 * 4 + 3) * 64];
        #pragma unroll
        for (int k = 0; k < 64; ++k) h1[k] = fmaf(xv.x, w0[k], h1[k]);
        #pragma unroll
        for (int k = 0; k < 64; ++k) h1[k] = fmaf(xv.y, w1[k], h1[k]);
        #pragma unroll
        for (int k = 0; k < 64; ++k) h1[k] = fmaf(xv.z, w2[k], h1[k]);
        #pragma unroll
        for (int k = 0; k < 64; ++k) h1[k] = fmaf(xv.w, w3[k], h1[k]);
    }
    #pragma unroll
    for (int k = 0; k < 64; ++k) sh1[t * 65 + k] = fmaxf(h1[k], 0.0f);

    // ---- layer 2: 64 -> 32 ----
    float h2[32];
    #pragma unroll
    for (int k = 0; k < 32; ++k) h2[k] = sb2[k];
    for (int j = 0; j < 64; ++j) {
        float a = sh1[t * 65 + j];
        #pragma unroll
        for (int k = 0; k < 32; ++k) h2[k] = fmaf(a, sW2[j * 32 + k], h2[k]);
    }
    #pragma unroll
    for (int k = 0; k < 32; ++k) sh2[t * 33 + k] = fmaxf(h2[k], 0.0f);

    // ---- layer 3: 32 -> 16 ----
    float h3[16];
    #pragma unroll
    for (int k = 0; k < 16; ++k) h3[k] = sb3[k];
    for (int j = 0; j < 32; ++j) {
        float a = sh2[t * 33 + j];
        #pragma unroll
        for (int k = 0; k < 16; ++k) h3[k] = fmaf(a, sW3[j * 16 + k], h3[k]);
    }
    #pragma unroll
    for (int k = 0; k < 16; ++k) sh3[t * 17 + k] = fmaxf(h3[k], 0.0f);

    // ---- layer 4: 16 -> 16, no relu ----
    float zo[16];
    #pragma unroll
    for (int k = 0; k < 16; ++k) zo[k] = sb4[k];
    for (int j = 0; j < 16; ++j) {
        float a = sh3[t * 17 + j];
        #pragma unroll
        for (int k = 0; k < 16; ++k) zo[k] = fmaf(a, sW4[j * 16 + k], zo[k]);
    }

    float s = 0.0f;
    #pragma unroll
    for (int k = 0; k < 16; ++k) s = fmaf(zo[k], zo[k], s);
    sqout[row] = s;
    float4* zr = (float4*)(z + (size_t)row * 16);
    zr[0] = make_float4(zo[0], zo[1], zo[2], zo[3]);
    zr[1] = make_float4(zo[4], zo[5], zo[6], zo[7]);
    zr[2] = make_float4(zo[8], zo[9], zo[10], zo[11]);
    zr[3] = make_float4(zo[12], zo[13], zo[14], zo[15]);
    // transposed copy: lane stride 4 B per k -> 16 perfectly coalesced stores
    #pragma unroll
    for (int k = 0; k < 16; ++k) zT[(size_t)k * N + row] = zo[k];
}

// ---------------------------------------------------------------------------
// Pass 1: complete row sums of numerator = 1/(1+dist). v4: restructured into
// the pass2-proven shape. Block owns 4 i-rows in registers (block-uniform);
// sweeps ALL 8192 j via contiguous 1-KB f32x4 loads from z_T (ZERO LDS ops
// in the steady state -- v1 issued 1024 broadcast ds_read_b128/thread, ~41 us
// of DS-pipe occupancy device-wide by the m134 12-cyc model). Each block
// covers the full j range, so it emits the COMPLETE row sum: the
// partial[NCHUNK][N] buffer and pass2's cross-chunk reduction disappear.
// Writes rowinv[i] = 1/rowsum directly. 2048 blocks.
// ---------------------------------------------------------------------------
__global__ __launch_bounds__(256) void pass1_kernel(
    const float* __restrict__ z, const float* __restrict__ zT,
    const float* __restrict__ sq, float* __restrict__ rowinv)
{
    __shared__ float s_part[4][4];   // [wave][row]

    int t = threadIdx.x;
    int ibase = blockIdx.x * 4;
    int w = t >> 6, lane = t & 63;

    float zi[4][16];
    float sqi[4];
    #pragma unroll
    for (int rr = 0; rr < 4; ++rr) {
        const float4* p = (const float4*)(z + (size_t)(ibase + rr) * 16);
        #pragma unroll
        for (int q = 0; q < 4; ++q) {
            float4 v = p[q];
            zi[rr][4*q]   = v.x; zi[rr][4*q+1] = v.y;
            zi[rr][4*q+2] = v.z; zi[rr][4*q+3] = v.w;
        }
        sqi[rr] = sq[ibase + rr];
    }

    float acc[4] = {0.0f, 0.0f, 0.0f, 0.0f};
    for (int jb = 0; jb < N; jb += 1024) {
        int j0 = jb + t * 4;
        f32x4 zjT[16];
        #pragma unroll
        for (int k = 0; k < 16; ++k)
            zjT[k] = *(const f32x4*)(zT + (size_t)k * N + j0);
        f32x4 sqj = *(const f32x4*)(sq + j0);

        #pragma unroll
        for (int rr = 0; rr < 4; ++rr) {
            f32x4 d = {0.0f, 0.0f, 0.0f, 0.0f};
            #pragma unroll
            for (int k = 0; k < 16; ++k) d += zi[rr][k] * zjT[k];
            f32x4 dist = sqi[rr] + sqj - 2.0f * d;
            acc[rr] += __builtin_amdgcn_rcpf(1.0f + fmaxf(dist.x, 0.0f))
                     + __builtin_amdgcn_rcpf(1.0f + fmaxf(dist.y, 0.0f))
                     + __builtin_amdgcn_rcpf(1.0f + fmaxf(dist.z, 0.0f))
                     + __builtin_amdgcn_rcpf(1.0f + fmaxf(dist.w, 0.0f));
        }
    }

    // block reduction: wave shuffle tree, then 4x4 LDS combine
    #pragma unroll
    for (int rr = 0; rr < 4; ++rr) {
        float v = acc[rr];
        #pragma unroll
        for (int off = 32; off > 0; off >>= 1) v += __shfl_xor(v, off, 64);
        if (lane == 0) s_part[w][rr] = v;
    }
    __syncthreads();
    if (t < 4) {
        float s = s_part[0][t] + s_part[1][t] + s_part[2][t] + s_part[3][t];
        rowinv[ibase + t] = 1.0f / s;
    }
}

// ---------------------------------------------------------------------------
// Pass 2: recompute numerators, scale by 1/rowsum, stream to out.
// Sweep identical to Round 3 (measured-good). Prologue simplified: rowinv is
// now precomputed by pass1, so the cross-chunk partial reduction is gone.
// ---------------------------------------------------------------------------
__global__ __launch_bounds__(256) void pass2_kernel(
    const float* __restrict__ z, const float* __restrict__ zT,
    const float* __restrict__ sq,
    const float* __restrict__ rowinv, float* __restrict__ out)
{
    __shared__ float s_inv[4];

    int t = threadIdx.x;
    int ibase = blockIdx.x * 4;

    if (t < 4) s_inv[t] = rowinv[ibase + t];

    float zi[4][16];
    float sqi[4];
    #pragma unroll
    for (int rr = 0; rr < 4; ++rr) {
        const float4* p = (const float4*)(z + (size_t)(ibase + rr) * 16);
        #pragma unroll
        for (int q = 0; q < 4; ++q) {
            float4 v = p[q];
            zi[rr][4*q]   = v.x; zi[rr][4*q+1] = v.y;
            zi[rr][4*q+2] = v.z; zi[rr][4*q+3] = v.w;
        }
        sqi[rr] = sq[ibase + rr];
    }
    __syncthreads();
    float inv[4];
    #pragma unroll
    for (int rr = 0; rr < 4; ++rr) inv[rr] = s_inv[rr];

    for (int jb = 0; jb < N; jb += 1024) {
        int j0 = jb + t * 4;
        // 16 contiguous 1-KB wave loads: zjT[k] = z^T[k][j0..j0+3]
        f32x4 zjT[16];
        #pragma unroll
        for (int k = 0; k < 16; ++k)
            zjT[k] = *(const f32x4*)(zT + (size_t)k * N + j0);
        f32x4 sqj = *(const f32x4*)(sq + j0);

        #pragma unroll
        for (int rr = 0; rr < 4; ++rr) {
            f32x4 d = {0.0f, 0.0f, 0.0f, 0.0f};
            #pragma unroll
            for (int k = 0; k < 16; ++k) d += zi[rr][k] * zjT[k];
            f32x4 dist = sqi[rr] + sqj - 2.0f * d;
            f32x4 num;
            num.x = __builtin_amdgcn_rcpf(1.0f + fmaxf(dist.x, 0.0f)) * inv[rr];
            num.y = __builtin_amdgcn_rcpf(1.0f + fmaxf(dist.y, 0.0f)) * inv[rr];
            num.z = __builtin_amdgcn_rcpf(1.0f + fmaxf(dist.z, 0.0f)) * inv[rr];
            num.w = __builtin_amdgcn_rcpf(1.0f + fmaxf(dist.w, 0.0f)) * inv[rr];
            __builtin_nontemporal_store(num,
                (f32x4*)(out + (size_t)(ibase + rr) * N + j0));
        }
    }
}

extern "C" void kernel_launch(void* const* d_in, const int* in_sizes, int n_in,
                              void* d_out, int out_size, void* d_ws, size_t ws_size,
                              hipStream_t stream) {
    const float* x  = (const float*)d_in[0];
    const float* W1 = (const float*)d_in[1];
    const float* b1 = (const float*)d_in[2];
    const float* W2 = (const float*)d_in[3];
    const float* b2 = (const float*)d_in[4];
    const float* W3 = (const float*)d_in[5];
    const float* b3 = (const float*)d_in[6];
    const float* W4 = (const float*)d_in[7];
    const float* b4 = (const float*)d_in[8];
    float* out = (float*)d_out;

    float* ws = (float*)d_ws;
    float* z      = ws;                 // N*16 = 131072 floats
    float* zT     = ws + N * 16;        // 16*N = 131072 floats
    float* sqv    = ws + N * 32;        // N    =   8192 floats
    float* rowinv = ws + N * 32 + N;    // N    =   8192 floats
    // total ws usage: 278528 floats = 1.06 MiB

    encoder_kernel<<<128, 64, 0, stream>>>(x, W1, b1, W2, b2, W3, b3, W4, b4, z, zT, sqv);
    pass1_kernel<<<N / 4, 256, 0, stream>>>(z, zT, sqv, rowinv);
    pass2_kernel<<<N / 4, 256, 0, stream>>>(z, zT, sqv, rowinv, out);
}

// Round 6
// 383.993 us; speedup vs baseline: 1.0138x; 1.0138x over previous
//
#include <hip/hip_runtime.h>

#define N 8192
#define DIM 128
#define NCHUNK 32   // j-chunks in pass 1 -> partial[NCHUNK][N]

typedef float f32x4 __attribute__((ext_vector_type(4)));

// ---------------------------------------------------------------------------
// Pass 0: encoder MLP. 128 -> 64 -> 32 -> 16 -> 16, relu on first three.
// Round-3 verbatim (measured-good): one thread per row, 64-thread blocks,
// weights in LDS, padded LDS columns for activations, plus the transposed
// copy z_T[16][N] via 16 coalesced scalar stores.
// ---------------------------------------------------------------------------
__global__ __launch_bounds__(64) void encoder_kernel(
    const float* __restrict__ x,
    const float* __restrict__ W1, const float* __restrict__ b1,
    const float* __restrict__ W2, const float* __restrict__ b2,
    const float* __restrict__ W3, const float* __restrict__ b3,
    const float* __restrict__ W4, const float* __restrict__ b4,
    float* __restrict__ z, float* __restrict__ zT, float* __restrict__ sqout)
{
    __shared__ float sW2[64 * 32];
    __shared__ float sW3[32 * 16];
    __shared__ float sW4[16 * 16];
    __shared__ float sb1[64];
    __shared__ float sb2[32];
    __shared__ float sb3[16];
    __shared__ float sb4[16];
    __shared__ float sW1[128 * 64];   // reused for h2/h3 staging after layer 1
    __shared__ float sh1[64 * 65];    // stride 65: bank = (t + k) % 32, conflict-free

    int t = threadIdx.x;
    float* sh2 = sW1;                 // 64*33 = 2112 floats
    float* sh3 = sW1 + 2112;          // 64*17 = 1088 floats  (3200 <= 8192, fits)

    for (int idx = t; idx < 128 * 64; idx += 64) sW1[idx] = W1[idx];
    for (int idx = t; idx < 64 * 32; idx += 64) sW2[idx] = W2[idx];
    for (int idx = t; idx < 32 * 16; idx += 64) sW3[idx] = W3[idx];
    for (int idx = t; idx < 16 * 16; idx += 64) sW4[idx] = W4[idx];
    sb1[t] = b1[t];
    if (t < 32) sb2[t] = b2[t];
    if (t < 16) { sb3[t] = b3[t]; sb4[t] = b4[t]; }
    __syncthreads();

    int row = blockIdx.x * 64 + t;
    const float4* xr = (const float4*)(x + (size_t)row * DIM);

    // ---- layer 1: 128 -> 64 ----
    float h1[64];
    #pragma unroll
    for (int k = 0; k < 64; ++k) h1[k] = sb1[k];
    for (int j4 = 0; j4 < 32; ++j4) {
        float4 xv = xr[j4];
        const float* w0 = &sW1[(j4 * 4 + 0) * 64];
        const float* w1 = &sW1[(j4 * 4 + 1) * 64];
        const float* w2 = &sW1[(j4 * 4 + 2) * 64];
        const float* w3 = &sW1[(j4 * 4 + 3) * 64];
        #pragma unroll
        for (int k = 0; k < 64; ++k) h1[k] = fmaf(xv.x, w0[k], h1[k]);
        #pragma unroll
        for (int k = 0; k < 64; ++k) h1[k] = fmaf(xv.y, w1[k], h1[k]);
        #pragma unroll
        for (int k = 0; k < 64; ++k) h1[k] = fmaf(xv.z, w2[k], h1[k]);
        #pragma unroll
        for (int k = 0; k < 64; ++k) h1[k] = fmaf(xv.w, w3[k], h1[k]);
    }
    #pragma unroll
    for (int k = 0; k < 64; ++k) sh1[t * 65 + k] = fmaxf(h1[k], 0.0f);

    // ---- layer 2: 64 -> 32 ----
    float h2[32];
    #pragma unroll
    for (int k = 0; k < 32; ++k) h2[k] = sb2[k];
    for (int j = 0; j < 64; ++j) {
        float a = sh1[t * 65 + j];
        #pragma unroll
        for (int k = 0; k < 32; ++k) h2[k] = fmaf(a, sW2[j * 32 + k], h2[k]);
    }
    #pragma unroll
    for (int k = 0; k < 32; ++k) sh2[t * 33 + k] = fmaxf(h2[k], 0.0f);

    // ---- layer 3: 32 -> 16 ----
    float h3[16];
    #pragma unroll
    for (int k = 0; k < 16; ++k) h3[k] = sb3[k];
    for (int j = 0; j < 32; ++j) {
        float a = sh2[t * 33 + j];
        #pragma unroll
        for (int k = 0; k < 16; ++k) h3[k] = fmaf(a, sW3[j * 16 + k], h3[k]);
    }
    #pragma unroll
    for (int k = 0; k < 16; ++k) sh3[t * 17 + k] = fmaxf(h3[k], 0.0f);

    // ---- layer 4: 16 -> 16, no relu ----
    float zo[16];
    #pragma unroll
    for (int k = 0; k < 16; ++k) zo[k] = sb4[k];
    for (int j = 0; j < 16; ++j) {
        float a = sh3[t * 17 + j];
        #pragma unroll
        for (int k = 0; k < 16; ++k) zo[k] = fmaf(a, sW4[j * 16 + k], zo[k]);
    }

    float s = 0.0f;
    #pragma unroll
    for (int k = 0; k < 16; ++k) s = fmaf(zo[k], zo[k], s);
    sqout[row] = s;
    float4* zr = (float4*)(z + (size_t)row * 16);
    zr[0] = make_float4(zo[0], zo[1], zo[2], zo[3]);
    zr[1] = make_float4(zo[4], zo[5], zo[6], zo[7]);
    zr[2] = make_float4(zo[8], zo[9], zo[10], zo[11]);
    zr[3] = make_float4(zo[12], zo[13], zo[14], zo[15]);
    // transposed copy: lane stride 4 B per k -> 16 perfectly coalesced stores
    #pragma unroll
    for (int k = 0; k < 16; ++k) zT[(size_t)k * N + row] = zo[k];
}

// ---------------------------------------------------------------------------
// Pass 1: row sums of numerator = 1/(1+dist). Grid (16 rowblocks, 32 jchunks).
// v1 verbatim (measured-good; the R4 full-sweep variant was +12 us: its 1 GiB
// of zT L2 re-reads cost more than these BROADCAST ds_read_b128s, which move
// only 16 B of LDS bandwidth each, not 1 KB -- the m134 12-cyc number does
// not apply to uniform-address reads).
// ---------------------------------------------------------------------------
__global__ __launch_bounds__(256) void pass1_kernel(
    const float* __restrict__ z, const float* __restrict__ sq,
    float* __restrict__ partial)
{
    __shared__ float s_zj[256 * 16];
    __shared__ float s_sqj[256];

    int t = threadIdx.x;
    int i0 = blockIdx.x * 256 + t;      // 0..4095
    int i1 = i0 + 4096;
    int jb = blockIdx.y * 256;

    // stage z tile for this block's j range
    {
        const float4* src = (const float4*)(z + (size_t)(jb + t) * 16);
        float4* dst = (float4*)(s_zj + t * 16);
        dst[0] = src[0]; dst[1] = src[1]; dst[2] = src[2]; dst[3] = src[3];
        s_sqj[t] = sq[jb + t];
    }

    float zi0[16], zi1[16];
    {
        const float4* p0 = (const float4*)(z + (size_t)i0 * 16);
        const float4* p1 = (const float4*)(z + (size_t)i1 * 16);
        #pragma unroll
        for (int q = 0; q < 4; ++q) {
            float4 v0 = p0[q]; float4 v1 = p1[q];
            zi0[4*q] = v0.x; zi0[4*q+1] = v0.y; zi0[4*q+2] = v0.z; zi0[4*q+3] = v0.w;
            zi1[4*q] = v1.x; zi1[4*q+1] = v1.y; zi1[4*q+2] = v1.z; zi1[4*q+3] = v1.w;
        }
    }
    float sqi0 = sq[i0], sqi1 = sq[i1];
    __syncthreads();

    float acc0 = 0.0f, acc1 = 0.0f;
    #pragma unroll 4
    for (int jj = 0; jj < 256; ++jj) {
        const float* zj = s_zj + jj * 16;
        float d0 = 0.0f, d1 = 0.0f;
        #pragma unroll
        for (int k = 0; k < 16; ++k) {
            float w = zj[k];
            d0 = fmaf(zi0[k], w, d0);
            d1 = fmaf(zi1[k], w, d1);
        }
        float sj = s_sqj[jj];
        float dist0 = fmaxf(fmaf(-2.0f, d0, sqi0 + sj), 0.0f);
        float dist1 = fmaxf(fmaf(-2.0f, d1, sqi1 + sj), 0.0f);
        acc0 += __builtin_amdgcn_rcpf(1.0f + dist0);
        acc1 += __builtin_amdgcn_rcpf(1.0f + dist1);
    }
    partial[blockIdx.y * N + i0] = acc0;
    partial[blockIdx.y * N + i1] = acc1;
}

// ---------------------------------------------------------------------------
// Pass 2: recompute numerators, scale by 1/rowsum, stream to out.
// v4 (the ONLY change vs Round 3): 8 i-rows per block (was 4), grid 1024.
// Halves the zT L2 re-read traffic (blocks x 512 KB: 1 GiB -> 512 MB) that
// shares the TCC pipe with the 256 MiB of NT stores, and doubles dot-reuse
// per loaded zjT. VGPR ~230 -> 8 waves/CU (was 12); 16 outstanding 1-KB
// loads/thread/iter should still cover latency.
// Prologue: 8 lane-groups of 32 reduce the NCHUNK=32 partials per row.
// ---------------------------------------------------------------------------
__global__ __launch_bounds__(256) void pass2_kernel(
    const float* __restrict__ z, const float* __restrict__ zT,
    const float* __restrict__ sq,
    const float* __restrict__ partial, float* __restrict__ out)
{
    __shared__ float s_inv[8];

    int t = threadIdx.x;
    int ibase = blockIdx.x * 8;
    int g = t >> 5, lane = t & 31;     // 8 groups of 32 lanes

    // rowsum: group g reduces the NCHUNK=32 partials of row ibase+g
    {
        float v = partial[(size_t)lane * N + ibase + g];
        #pragma unroll
        for (int off = 16; off > 0; off >>= 1) v += __shfl_xor(v, off, 32);
        if (lane == 0) s_inv[g] = 1.0f / v;
    }

    float zi[8][16];
    float sqi[8];
    #pragma unroll
    for (int rr = 0; rr < 8; ++rr) {
        const float4* p = (const float4*)(z + (size_t)(ibase + rr) * 16);
        #pragma unroll
        for (int q = 0; q < 4; ++q) {
            float4 v = p[q];
            zi[rr][4*q]   = v.x; zi[rr][4*q+1] = v.y;
            zi[rr][4*q+2] = v.z; zi[rr][4*q+3] = v.w;
        }
        sqi[rr] = sq[ibase + rr];
    }
    __syncthreads();
    float inv[8];
    #pragma unroll
    for (int rr = 0; rr < 8; ++rr) inv[rr] = s_inv[rr];

    for (int jb = 0; jb < N; jb += 1024) {
        int j0 = jb + t * 4;
        // 16 contiguous 1-KB wave loads: zjT[k] = z^T[k][j0..j0+3]
        f32x4 zjT[16];
        #pragma unroll
        for (int k = 0; k < 16; ++k)
            zjT[k] = *(const f32x4*)(zT + (size_t)k * N + j0);
        f32x4 sqj = *(const f32x4*)(sq + j0);

        #pragma unroll
        for (int rr = 0; rr < 8; ++rr) {
            f32x4 d = {0.0f, 0.0f, 0.0f, 0.0f};
            #pragma unroll
            for (int k = 0; k < 16; ++k) d += zi[rr][k] * zjT[k];
            f32x4 dist = sqi[rr] + sqj - 2.0f * d;
            f32x4 num;
            num.x = __builtin_amdgcn_rcpf(1.0f + fmaxf(dist.x, 0.0f)) * inv[rr];
            num.y = __builtin_amdgcn_rcpf(1.0f + fmaxf(dist.y, 0.0f)) * inv[rr];
            num.z = __builtin_amdgcn_rcpf(1.0f + fmaxf(dist.z, 0.0f)) * inv[rr];
            num.w = __builtin_amdgcn_rcpf(1.0f + fmaxf(dist.w, 0.0f)) * inv[rr];
            __builtin_nontemporal_store(num,
                (f32x4*)(out + (size_t)(ibase + rr) * N + j0));
        }
    }
}

extern "C" void kernel_launch(void* const* d_in, const int* in_sizes, int n_in,
                              void* d_out, int out_size, void* d_ws, size_t ws_size,
                              hipStream_t stream) {
    const float* x  = (const float*)d_in[0];
    const float* W1 = (const float*)d_in[1];
    const float* b1 = (const float*)d_in[2];
    const float* W2 = (const float*)d_in[3];
    const float* b2 = (const float*)d_in[4];
    const float* W3 = (const float*)d_in[5];
    const float* b3 = (const float*)d_in[6];
    const float* W4 = (const float*)d_in[7];
    const float* b4 = (const float*)d_in[8];
    float* out = (float*)d_out;

    float* ws = (float*)d_ws;
    float* z       = ws;                        // N*16     = 131072 floats
    float* zT      = ws + N * 16;               // 16*N     = 131072 floats
    float* sqv     = ws + N * 32;               // N        =   8192 floats
    float* partial = ws + N * 32 + N;           // NCHUNK*N = 262144 floats
    // total ws usage: 532480 floats = 2.03 MiB

    encoder_kernel<<<128, 64, 0, stream>>>(x, W1, b1, W2, b2, W3, b3, W4, b4, z, zT, sqv);
    pass1_kernel<<<dim3(16, NCHUNK), 256, 0, stream>>>(z, sqv, partial);
    pass2_kernel<<<N / 8, 256, 0, stream>>>(z, zT, sqv, partial, out);
}

// Round 7
// 361.858 us; speedup vs baseline: 1.0758x; 1.0612x over previous
//
#include <hip/hip_runtime.h>

#define N 8192
#define DIM 128
#define NCHUNK 32   // j-chunks in pass 1 -> partial[NCHUNK][N]

typedef float f32x4 __attribute__((ext_vector_type(4)));

// ---------------------------------------------------------------------------
// Pass 0: encoder MLP. 128 -> 64 -> 32 -> 16 -> 16, relu on first three.
// v2 (the ONLY change vs the 376.9-us R3 config): TWO threads per row
// (t&31 = row, t>>5 = output-half). 256 blocks x 64 threads -> one wave on
// EVERY CU (R3: 128 single-wave blocks = half the CUs idle at 1 wave/SIMD),
// per-thread FMA count halved. Cross-half activation exchange via LDS;
// block = one wave, so LDS program order makes write-before-read safe (the
// same property R3's sW1/sh2 aliasing relies on). Emits z, z_T, sq.
// ---------------------------------------------------------------------------
__global__ __launch_bounds__(64) void encoder_kernel(
    const float* __restrict__ x,
    const float* __restrict__ W1, const float* __restrict__ b1,
    const float* __restrict__ W2, const float* __restrict__ b2,
    const float* __restrict__ W3, const float* __restrict__ b3,
    const float* __restrict__ W4, const float* __restrict__ b4,
    float* __restrict__ z, float* __restrict__ zT, float* __restrict__ sqout)
{
    __shared__ float sW1[128 * 64];
    __shared__ float sW2[64 * 32];
    __shared__ float sW3[32 * 16];
    __shared__ float sW4[16 * 16];
    __shared__ float sb1[64];
    __shared__ float sb2[32];
    __shared__ float sb3[16];
    __shared__ float sb4[16];
    __shared__ float sh1[32 * 65];   // 32 rows, stride 65: conflict-light
    __shared__ float sh2[32 * 33];
    __shared__ float sh3[32 * 17];

    int t = threadIdx.x;
    int r = t & 31;    // local row
    int h = t >> 5;    // output half (0/1)

    for (int idx = t; idx < 128 * 64; idx += 64) sW1[idx] = W1[idx];
    for (int idx = t; idx < 64 * 32; idx += 64) sW2[idx] = W2[idx];
    for (int idx = t; idx < 32 * 16; idx += 64) sW3[idx] = W3[idx];
    for (int idx = t; idx < 16 * 16; idx += 64) sW4[idx] = W4[idx];
    sb1[t] = b1[t];
    if (t < 32) sb2[t] = b2[t];
    if (t < 16) { sb3[t] = b3[t]; sb4[t] = b4[t]; }
    __syncthreads();

    int row = blockIdx.x * 32 + r;
    const float4* xr = (const float4*)(x + (size_t)row * DIM);

    // ---- layer 1: 128 -> 64, this thread computes outputs [h*32, h*32+32) ----
    float h1[32];
    #pragma unroll
    for (int k = 0; k < 32; ++k) h1[k] = sb1[h * 32 + k];
    for (int j4 = 0; j4 < 32; ++j4) {
        float4 xv = xr[j4];
        const float* w0 = &sW1[(j4 * 4 + 0) * 64 + h * 32];
        const float* w1 = &sW1[(j4 * 4 + 1) * 64 + h * 32];
        const float* w2 = &sW1[(j4 * 4 + 2) * 64 + h * 32];
        const float* w3 = &sW1[(j4 * 4 + 3) * 64 + h * 32];
        #pragma unroll
        for (int k = 0; k < 32; ++k) h1[k] = fmaf(xv.x, w0[k], h1[k]);
        #pragma unroll
        for (int k = 0; k < 32; ++k) h1[k] = fmaf(xv.y, w1[k], h1[k]);
        #pragma unroll
        for (int k = 0; k < 32; ++k) h1[k] = fmaf(xv.z, w2[k], h1[k]);
        #pragma unroll
        for (int k = 0; k < 32; ++k) h1[k] = fmaf(xv.w, w3[k], h1[k]);
    }
    #pragma unroll
    for (int k = 0; k < 32; ++k) sh1[r * 65 + h * 32 + k] = fmaxf(h1[k], 0.0f);

    // ---- layer 2: 64 -> 32, outputs [h*16, h*16+16), inputs all 64 ----
    // (single-wave block: layer-1 LDS writes precede these reads in program order)
    float h2[16];
    #pragma unroll
    for (int k = 0; k < 16; ++k) h2[k] = sb2[h * 16 + k];
    for (int j = 0; j < 64; ++j) {
        float a = sh1[r * 65 + j];
        #pragma unroll
        for (int k = 0; k < 16; ++k) h2[k] = fmaf(a, sW2[j * 32 + h * 16 + k], h2[k]);
    }
    #pragma unroll
    for (int k = 0; k < 16; ++k) sh2[r * 33 + h * 16 + k] = fmaxf(h2[k], 0.0f);

    // ---- layer 3: 32 -> 16, outputs [h*8, h*8+8) ----
    float h3[8];
    #pragma unroll
    for (int k = 0; k < 8; ++k) h3[k] = sb3[h * 8 + k];
    for (int j = 0; j < 32; ++j) {
        float a = sh2[r * 33 + j];
        #pragma unroll
        for (int k = 0; k < 8; ++k) h3[k] = fmaf(a, sW3[j * 16 + h * 8 + k], h3[k]);
    }
    #pragma unroll
    for (int k = 0; k < 8; ++k) sh3[r * 17 + h * 8 + k] = fmaxf(h3[k], 0.0f);

    // ---- layer 4: 16 -> 16, no relu, outputs [h*8, h*8+8) ----
    float zo[8];
    #pragma unroll
    for (int k = 0; k < 8; ++k) zo[k] = sb4[h * 8 + k];
    for (int j = 0; j < 16; ++j) {
        float a = sh3[r * 17 + j];
        #pragma unroll
        for (int k = 0; k < 8; ++k) zo[k] = fmaf(a, sW4[j * 16 + h * 8 + k], zo[k]);
    }

    float s = 0.0f;
    #pragma unroll
    for (int k = 0; k < 8; ++k) s = fmaf(zo[k], zo[k], s);
    s += __shfl_xor(s, 32, 64);          // combine the two halves' partial sums
    if (h == 0) sqout[row] = s;
    float4* zr = (float4*)(z + (size_t)row * 16 + h * 8);
    zr[0] = make_float4(zo[0], zo[1], zo[2], zo[3]);
    zr[1] = make_float4(zo[4], zo[5], zo[6], zo[7]);
    // transposed copy: for fixed k, 32 lanes store 32 consecutive rows
    #pragma unroll
    for (int k = 0; k < 8; ++k) zT[(size_t)(h * 8 + k) * N + row] = zo[k];
}

// ---------------------------------------------------------------------------
// Pass 1: row sums of numerator = 1/(1+dist). Grid (16 rowblocks, 32 jchunks).
// R3 verbatim (measured-good; the R4 full-sweep variant was +12 us: its 1 GiB
// of zT L2 re-reads cost more than these BROADCAST ds_read_b128s, which move
// only 16 B of LDS bandwidth each, not 1 KB).
// ---------------------------------------------------------------------------
__global__ __launch_bounds__(256) void pass1_kernel(
    const float* __restrict__ z, const float* __restrict__ sq,
    float* __restrict__ partial)
{
    __shared__ float s_zj[256 * 16];
    __shared__ float s_sqj[256];

    int t = threadIdx.x;
    int i0 = blockIdx.x * 256 + t;      // 0..4095
    int i1 = i0 + 4096;
    int jb = blockIdx.y * 256;

    // stage z tile for this block's j range
    {
        const float4* src = (const float4*)(z + (size_t)(jb + t) * 16);
        float4* dst = (float4*)(s_zj + t * 16);
        dst[0] = src[0]; dst[1] = src[1]; dst[2] = src[2]; dst[3] = src[3];
        s_sqj[t] = sq[jb + t];
    }

    float zi0[16], zi1[16];
    {
        const float4* p0 = (const float4*)(z + (size_t)i0 * 16);
        const float4* p1 = (const float4*)(z + (size_t)i1 * 16);
        #pragma unroll
        for (int q = 0; q < 4; ++q) {
            float4 v0 = p0[q]; float4 v1 = p1[q];
            zi0[4*q] = v0.x; zi0[4*q+1] = v0.y; zi0[4*q+2] = v0.z; zi0[4*q+3] = v0.w;
            zi1[4*q] = v1.x; zi1[4*q+1] = v1.y; zi1[4*q+2] = v1.z; zi1[4*q+3] = v1.w;
        }
    }
    float sqi0 = sq[i0], sqi1 = sq[i1];
    __syncthreads();

    float acc0 = 0.0f, acc1 = 0.0f;
    #pragma unroll 4
    for (int jj = 0; jj < 256; ++jj) {
        const float* zj = s_zj + jj * 16;
        float d0 = 0.0f, d1 = 0.0f;
        #pragma unroll
        for (int k = 0; k < 16; ++k) {
            float w = zj[k];
            d0 = fmaf(zi0[k], w, d0);
            d1 = fmaf(zi1[k], w, d1);
        }
        float sj = s_sqj[jj];
        float dist0 = fmaxf(fmaf(-2.0f, d0, sqi0 + sj), 0.0f);
        float dist1 = fmaxf(fmaf(-2.0f, d1, sqi1 + sj), 0.0f);
        acc0 += __builtin_amdgcn_rcpf(1.0f + dist0);
        acc1 += __builtin_amdgcn_rcpf(1.0f + dist1);
    }
    partial[blockIdx.y * N + i0] = acc0;
    partial[blockIdx.y * N + i1] = acc1;
}

// ---------------------------------------------------------------------------
// Pass 2: recompute numerators, scale by 1/rowsum, stream to out.
// R3 verbatim, 4 i-rows per block, grid 2048 (LOCKED: R6 measured 8-row at
// +7 us -> pass2 is HBM-store/latency-bound, not L2-contention-bound; the
// occupancy drop from VGPR ~230 cost more than the halved L2 re-reads saved).
// ---------------------------------------------------------------------------
__global__ __launch_bounds__(256) void pass2_kernel(
    const float* __restrict__ z, const float* __restrict__ zT,
    const float* __restrict__ sq,
    const float* __restrict__ partial, float* __restrict__ out)
{
    __shared__ float s_inv[4];

    int t = threadIdx.x;
    int ibase = blockIdx.x * 4;
    int w = t >> 6, lane = t & 63;

    // rowsum: wave w reduces the NCHUNK=32 partials of row ibase+w
    {
        float v = (lane < NCHUNK) ? partial[(size_t)lane * N + ibase + w] : 0.0f;
        #pragma unroll
        for (int off = 32; off > 0; off >>= 1) v += __shfl_xor(v, off, 64);
        if (lane == 0) s_inv[w] = 1.0f / v;
    }

    float zi[4][16];
    float sqi[4];
    #pragma unroll
    for (int rr = 0; rr < 4; ++rr) {
        const float4* p = (const float4*)(z + (size_t)(ibase + rr) * 16);
        #pragma unroll
        for (int q = 0; q < 4; ++q) {
            float4 v = p[q];
            zi[rr][4*q]   = v.x; zi[rr][4*q+1] = v.y;
            zi[rr][4*q+2] = v.z; zi[rr][4*q+3] = v.w;
        }
        sqi[rr] = sq[ibase + rr];
    }
    __syncthreads();
    float inv[4];
    #pragma unroll
    for (int rr = 0; rr < 4; ++rr) inv[rr] = s_inv[rr];

    for (int jb = 0; jb < N; jb += 1024) {
        int j0 = jb + t * 4;
        // 16 contiguous 1-KB wave loads: zjT[k] = z^T[k][j0..j0+3]
        f32x4 zjT[16];
        #pragma unroll
        for (int k = 0; k < 16; ++k)
            zjT[k] = *(const f32x4*)(zT + (size_t)k * N + j0);
        f32x4 sqj = *(const f32x4*)(sq + j0);

        #pragma unroll
        for (int rr = 0; rr < 4; ++rr) {
            f32x4 d = {0.0f, 0.0f, 0.0f, 0.0f};
            #pragma unroll
            for (int k = 0; k < 16; ++k) d += zi[rr][k] * zjT[k];
            f32x4 dist = sqi[rr] + sqj - 2.0f * d;
            f32x4 num;
            num.x = __builtin_amdgcn_rcpf(1.0f + fmaxf(dist.x, 0.0f)) * inv[rr];
            num.y = __builtin_amdgcn_rcpf(1.0f + fmaxf(dist.y, 0.0f)) * inv[rr];
            num.z = __builtin_amdgcn_rcpf(1.0f + fmaxf(dist.z, 0.0f)) * inv[rr];
            num.w = __builtin_amdgcn_rcpf(1.0f + fmaxf(dist.w, 0.0f)) * inv[rr];
            __builtin_nontemporal_store(num,
                (f32x4*)(out + (size_t)(ibase + rr) * N + j0));
        }
    }
}

extern "C" void kernel_launch(void* const* d_in, const int* in_sizes, int n_in,
                              void* d_out, int out_size, void* d_ws, size_t ws_size,
                              hipStream_t stream) {
    const float* x  = (const float*)d_in[0];
    const float* W1 = (const float*)d_in[1];
    const float* b1 = (const float*)d_in[2];
    const float* W2 = (const float*)d_in[3];
    const float* b2 = (const float*)d_in[4];
    const float* W3 = (const float*)d_in[5];
    const float* b3 = (const float*)d_in[6];
    const float* W4 = (const float*)d_in[7];
    const float* b4 = (const float*)d_in[8];
    float* out = (float*)d_out;

    float* ws = (float*)d_ws;
    float* z       = ws;                        // N*16     = 131072 floats
    float* zT      = ws + N * 16;               // 16*N     = 131072 floats
    float* sqv     = ws + N * 32;               // N        =   8192 floats
    float* partial = ws + N * 32 + N;           // NCHUNK*N = 262144 floats
    // total ws usage: 532480 floats = 2.03 MiB

    encoder_kernel<<<256, 64, 0, stream>>>(x, W1, b1, W2, b2, W3, b3, W4, b4, z, zT, sqv);
    pass1_kernel<<<dim3(16, NCHUNK), 256, 0, stream>>>(z, sqv, partial);
    pass2_kernel<<<N / 4, 256, 0, stream>>>(z, zT, sqv, partial, out);
}

// Round 9
// 360.633 us; speedup vs baseline: 1.0794x; 1.0034x over previous
//
#include <hip/hip_runtime.h>

#define N 8192
#define DIM 128
#define NCHUNK 32   // j-chunks in pass 1 -> partial[NCHUNK][N]

typedef float f32x4 __attribute__((ext_vector_type(4)));
typedef float f32x2 __attribute__((ext_vector_type(2)));

// ---------------------------------------------------------------------------
// Pass 0: encoder MLP. 128 -> 64 -> 32 -> 16 -> 16, relu on first three.
// R7 verbatim (measured-good, -15 us vs single-thread-per-row): TWO threads
// per row (t&31 = row, t>>5 = output-half), 256 blocks x 64 threads -> one
// wave on EVERY CU. Cross-half activation exchange via LDS; block = one
// wave, so LDS program order makes write-before-read safe.
// ---------------------------------------------------------------------------
__global__ __launch_bounds__(64) void encoder_kernel(
    const float* __restrict__ x,
    const float* __restrict__ W1, const float* __restrict__ b1,
    const float* __restrict__ W2, const float* __restrict__ b2,
    const float* __restrict__ W3, const float* __restrict__ b3,
    const float* __restrict__ W4, const float* __restrict__ b4,
    float* __restrict__ z, float* __restrict__ zT, float* __restrict__ sqout)
{
    __shared__ float sW1[128 * 64];
    __shared__ float sW2[64 * 32];
    __shared__ float sW3[32 * 16];
    __shared__ float sW4[16 * 16];
    __shared__ float sb1[64];
    __shared__ float sb2[32];
    __shared__ float sb3[16];
    __shared__ float sb4[16];
    __shared__ float sh1[32 * 65];   // 32 rows, stride 65: conflict-light
    __shared__ float sh2[32 * 33];
    __shared__ float sh3[32 * 17];

    int t = threadIdx.x;
    int r = t & 31;    // local row
    int h = t >> 5;    // output half (0/1)

    for (int idx = t; idx < 128 * 64; idx += 64) sW1[idx] = W1[idx];
    for (int idx = t; idx < 64 * 32; idx += 64) sW2[idx] = W2[idx];
    for (int idx = t; idx < 32 * 16; idx += 64) sW3[idx] = W3[idx];
    for (int idx = t; idx < 16 * 16; idx += 64) sW4[idx] = W4[idx];
    sb1[t] = b1[t];
    if (t < 32) sb2[t] = b2[t];
    if (t < 16) { sb3[t] = b3[t]; sb4[t] = b4[t]; }
    __syncthreads();

    int row = blockIdx.x * 32 + r;
    const float4* xr = (const float4*)(x + (size_t)row * DIM);

    // ---- layer 1: 128 -> 64, this thread computes outputs [h*32, h*32+32) ----
    float h1[32];
    #pragma unroll
    for (int k = 0; k < 32; ++k) h1[k] = sb1[h * 32 + k];
    for (int j4 = 0; j4 < 32; ++j4) {
        float4 xv = xr[j4];
        const float* w0 = &sW1[(j4 * 4 + 0) * 64 + h * 32];
        const float* w1 = &sW1[(j4 * 4 + 1) * 64 + h * 32];
        const float* w2 = &sW1[(j4 * 4 + 2) * 64 + h * 32];
        const float* w3 = &sW1[(j4 * 4 + 3) * 64 + h * 32];
        #pragma unroll
        for (int k = 0; k < 32; ++k) h1[k] = fmaf(xv.x, w0[k], h1[k]);
        #pragma unroll
        for (int k = 0; k < 32; ++k) h1[k] = fmaf(xv.y, w1[k], h1[k]);
        #pragma unroll
        for (int k = 0; k < 32; ++k) h1[k] = fmaf(xv.z, w2[k], h1[k]);
        #pragma unroll
        for (int k = 0; k < 32; ++k) h1[k] = fmaf(xv.w, w3[k], h1[k]);
    }
    #pragma unroll
    for (int k = 0; k < 32; ++k) sh1[r * 65 + h * 32 + k] = fmaxf(h1[k], 0.0f);

    // ---- layer 2: 64 -> 32, outputs [h*16, h*16+16), inputs all 64 ----
    float h2[16];
    #pragma unroll
    for (int k = 0; k < 16; ++k) h2[k] = sb2[h * 16 + k];
    for (int j = 0; j < 64; ++j) {
        float a = sh1[r * 65 + j];
        #pragma unroll
        for (int k = 0; k < 16; ++k) h2[k] = fmaf(a, sW2[j * 32 + h * 16 + k], h2[k]);
    }
    #pragma unroll
    for (int k = 0; k < 16; ++k) sh2[r * 33 + h * 16 + k] = fmaxf(h2[k], 0.0f);

    // ---- layer 3: 32 -> 16, outputs [h*8, h*8+8) ----
    float h3[8];
    #pragma unroll
    for (int k = 0; k < 8; ++k) h3[k] = sb3[h * 8 + k];
    for (int j = 0; j < 32; ++j) {
        float a = sh2[r * 33 + j];
        #pragma unroll
        for (int k = 0; k < 8; ++k) h3[k] = fmaf(a, sW3[j * 16 + h * 8 + k], h3[k]);
    }
    #pragma unroll
    for (int k = 0; k < 8; ++k) sh3[r * 17 + h * 8 + k] = fmaxf(h3[k], 0.0f);

    // ---- layer 4: 16 -> 16, no relu, outputs [h*8, h*8+8) ----
    float zo[8];
    #pragma unroll
    for (int k = 0; k < 8; ++k) zo[k] = sb4[h * 8 + k];
    for (int j = 0; j < 16; ++j) {
        float a = sh3[r * 17 + j];
        #pragma unroll
        for (int k = 0; k < 8; ++k) zo[k] = fmaf(a, sW4[j * 16 + h * 8 + k], zo[k]);
    }

    float s = 0.0f;
    #pragma unroll
    for (int k = 0; k < 8; ++k) s = fmaf(zo[k], zo[k], s);
    s += __shfl_xor(s, 32, 64);          // combine the two halves' partial sums
    if (h == 0) sqout[row] = s;
    float4* zr = (float4*)(z + (size_t)row * 16 + h * 8);
    zr[0] = make_float4(zo[0], zo[1], zo[2], zo[3]);
    zr[1] = make_float4(zo[4], zo[5], zo[6], zo[7]);
    // transposed copy: for fixed k, 32 lanes store 32 consecutive rows
    #pragma unroll
    for (int k = 0; k < 8; ++k) zT[(size_t)(h * 8 + k) * N + row] = zo[k];
}

// ---------------------------------------------------------------------------
// Pass 1: row sums of numerator = 1/(1+dist). Grid (16 rowblocks, 32 jchunks).
// v3 (the ONLY change this round): inner dot vectorized to f32x2 so the
// compiler can emit v_pk_fma_f32 (VOP3P packed FP32, 2x scalar v_fma rate --
// the 157 TF vector-FP32 figure requires it). 16 scalar FMA/row/j -> 8
// pk-FMA + 1 horizontal add. Epilogue folds the +1 into precomputed (1+sqi):
// max(a,0)+1 == max(a+1,1) exactly, saving 2 insts/j. LDS reads remain
// float4 (ds_read_b128, broadcast), reinterpreted to pairs in registers.
// Structure/grid/staging identical to the measured-good R3 kernel.
// ---------------------------------------------------------------------------
__global__ __launch_bounds__(256) void pass1_kernel(
    const float* __restrict__ z, const float* __restrict__ sq,
    float* __restrict__ partial)
{
    __shared__ float s_zj[256 * 16];
    __shared__ float s_sqj[256];

    int t = threadIdx.x;
    int i0 = blockIdx.x * 256 + t;      // 0..4095
    int i1 = i0 + 4096;
    int jb = blockIdx.y * 256;

    // stage z tile for this block's j range
    {
        const float4* src = (const float4*)(z + (size_t)(jb + t) * 16);
        float4* dst = (float4*)(s_zj + t * 16);
        dst[0] = src[0]; dst[1] = src[1]; dst[2] = src[2]; dst[3] = src[3];
        s_sqj[t] = sq[jb + t];
    }

    f32x2 zi0[8], zi1[8];
    {
        const float4* p0 = (const float4*)(z + (size_t)i0 * 16);
        const float4* p1 = (const float4*)(z + (size_t)i1 * 16);
        #pragma unroll
        for (int q = 0; q < 4; ++q) {
            float4 v0 = p0[q]; float4 v1 = p1[q];
            zi0[2*q]   = f32x2{v0.x, v0.y}; zi0[2*q+1] = f32x2{v0.z, v0.w};
            zi1[2*q]   = f32x2{v1.x, v1.y}; zi1[2*q+1] = f32x2{v1.z, v1.w};
        }
    }
    float sqi0p = 1.0f + sq[i0], sqi1p = 1.0f + sq[i1];
    __syncthreads();

    float acc0 = 0.0f, acc1 = 0.0f;
    #pragma unroll 4
    for (int jj = 0; jj < 256; ++jj) {
        const float4* zj4 = (const float4*)(s_zj + jj * 16);
        f32x2 d0 = {0.0f, 0.0f}, d1 = {0.0f, 0.0f};
        #pragma unroll
        for (int q = 0; q < 4; ++q) {
            float4 v = zj4[q];                 // ds_read_b128 broadcast
            f32x2 wa = {v.x, v.y}, wb = {v.z, v.w};
            d0 += zi0[2*q] * wa;               // v_pk_fma_f32 (hoped)
            d0 += zi0[2*q+1] * wb;
            d1 += zi1[2*q] * wa;
            d1 += zi1[2*q+1] * wb;
        }
        float s0 = d0.x + d0.y, s1 = d1.x + d1.y;
        float sj = s_sqj[jj];
        // dist+1 = max((1+sqi)+sj - 2*dot, 1): exact (max(a,0)+1 == max(a+1,1))
        acc0 += __builtin_amdgcn_rcpf(fmaxf(fmaf(-2.0f, s0, sqi0p + sj), 1.0f));
        acc1 += __builtin_amdgcn_rcpf(fmaxf(fmaf(-2.0f, s1, sqi1p + sj), 1.0f));
    }
    partial[blockIdx.y * N + i0] = acc0;
    partial[blockIdx.y * N + i1] = acc1;
}

// ---------------------------------------------------------------------------
// Pass 2: recompute numerators, scale by 1/rowsum, stream to out.
// R3 verbatim, 4 i-rows per block, grid 2048 (LOCKED: R6 measured 8-row at
// +7 us -> pass2 is HBM-store/latency-bound; occupancy matters more than L2
// re-read volume).
// ---------------------------------------------------------------------------
__global__ __launch_bounds__(256) void pass2_kernel(
    const float* __restrict__ z, const float* __restrict__ zT,
    const float* __restrict__ sq,
    const float* __restrict__ partial, float* __restrict__ out)
{
    __shared__ float s_inv[4];

    int t = threadIdx.x;
    int ibase = blockIdx.x * 4;
    int w = t >> 6, lane = t & 63;

    // rowsum: wave w reduces the NCHUNK=32 partials of row ibase+w
    {
        float v = (lane < NCHUNK) ? partial[(size_t)lane * N + ibase + w] : 0.0f;
        #pragma unroll
        for (int off = 32; off > 0; off >>= 1) v += __shfl_xor(v, off, 64);
        if (lane == 0) s_inv[w] = 1.0f / v;
    }

    float zi[4][16];
    float sqi[4];
    #pragma unroll
    for (int rr = 0; rr < 4; ++rr) {
        const float4* p = (const float4*)(z + (size_t)(ibase + rr) * 16);
        #pragma unroll
        for (int q = 0; q < 4; ++q) {
            float4 v = p[q];
            zi[rr][4*q]   = v.x; zi[rr][4*q+1] = v.y;
            zi[rr][4*q+2] = v.z; zi[rr][4*q+3] = v.w;
        }
        sqi[rr] = sq[ibase + rr];
    }
    __syncthreads();
    float inv[4];
    #pragma unroll
    for (int rr = 0; rr < 4; ++rr) inv[rr] = s_inv[rr];

    for (int jb = 0; jb < N; jb += 1024) {
        int j0 = jb + t * 4;
        // 16 contiguous 1-KB wave loads: zjT[k] = z^T[k][j0..j0+3]
        f32x4 zjT[16];
        #pragma unroll
        for (int k = 0; k < 16; ++k)
            zjT[k] = *(const f32x4*)(zT + (size_t)k * N + j0);
        f32x4 sqj = *(const f32x4*)(sq + j0);

        #pragma unroll
        for (int rr = 0; rr < 4; ++rr) {
            f32x4 d = {0.0f, 0.0f, 0.0f, 0.0f};
            #pragma unroll
            for (int k = 0; k < 16; ++k) d += zi[rr][k] * zjT[k];
            f32x4 dist = sqi[rr] + sqj - 2.0f * d;
            f32x4 num;
            num.x = __builtin_amdgcn_rcpf(1.0f + fmaxf(dist.x, 0.0f)) * inv[rr];
            num.y = __builtin_amdgcn_rcpf(1.0f + fmaxf(dist.y, 0.0f)) * inv[rr];
            num.z = __builtin_amdgcn_rcpf(1.0f + fmaxf(dist.z, 0.0f)) * inv[rr];
            num.w = __builtin_amdgcn_rcpf(1.0f + fmaxf(dist.w, 0.0f)) * inv[rr];
            __builtin_nontemporal_store(num,
                (f32x4*)(out + (size_t)(ibase + rr) * N + j0));
        }
    }
}

extern "C" void kernel_launch(void* const* d_in, const int* in_sizes, int n_in,
                              void* d_out, int out_size, void* d_ws, size_t ws_size,
                              hipStream_t stream) {
    const float* x  = (const float*)d_in[0];
    const float* W1 = (const float*)d_in[1];
    const float* b1 = (const float*)d_in[2];
    const float* W2 = (const float*)d_in[3];
    const float* b2 = (const float*)d_in[4];
    const float* W3 = (const float*)d_in[5];
    const float* b3 = (const float*)d_in[6];
    const float* W4 = (const float*)d_in[7];
    const float* b4 = (const float*)d_in[8];
    float* out = (float*)d_out;

    float* ws = (float*)d_ws;
    float* z       = ws;                        // N*16     = 131072 floats
    float* zT      = ws + N * 16;               // 16*N     = 131072 floats
    float* sqv     = ws + N * 32;               // N        =   8192 floats
    float* partial = ws + N * 32 + N;           // NCHUNK*N = 262144 floats
    // total ws usage: 532480 floats = 2.03 MiB

    encoder_kernel<<<256, 64, 0, stream>>>(x, W1, b1, W2, b2, W3, b3, W4, b4, z, zT, sqv);
    pass1_kernel<<<dim3(16, NCHUNK), 256, 0, stream>>>(z, sqv, partial);
    pass2_kernel<<<N / 4, 256, 0, stream>>>(z, zT, sqv, partial, out);
}

// Round 11
// 356.992 us; speedup vs baseline: 1.0905x; 1.0102x over previous
//
#include <hip/hip_runtime.h>

#define N 8192
#define DIM 128
#define NCHUNK 64            // j-chunks in pass 1 -> partial[NCHUNK][N]
#define JTILE (N / NCHUNK)   // 128 j per pass-1 block

typedef float f32x4 __attribute__((ext_vector_type(4)));
typedef float f32x2 __attribute__((ext_vector_type(2)));

// ---------------------------------------------------------------------------
// Pass 0: encoder MLP. 128 -> 64 -> 32 -> 16 -> 16, relu on first three.
// R7 verbatim (measured-good, -15 us vs single-thread-per-row): TWO threads
// per row (t&31 = row, t>>5 = output-half), 256 blocks x 64 threads -> one
// wave on EVERY CU. Cross-half activation exchange via LDS; block = one
// wave, so LDS program order makes write-before-read safe.
// ---------------------------------------------------------------------------
__global__ __launch_bounds__(64) void encoder_kernel(
    const float* __restrict__ x,
    const float* __restrict__ W1, const float* __restrict__ b1,
    const float* __restrict__ W2, const float* __restrict__ b2,
    const float* __restrict__ W3, const float* __restrict__ b3,
    const float* __restrict__ W4, const float* __restrict__ b4,
    float* __restrict__ z, float* __restrict__ zT, float* __restrict__ sqout)
{
    __shared__ float sW1[128 * 64];
    __shared__ float sW2[64 * 32];
    __shared__ float sW3[32 * 16];
    __shared__ float sW4[16 * 16];
    __shared__ float sb1[64];
    __shared__ float sb2[32];
    __shared__ float sb3[16];
    __shared__ float sb4[16];
    __shared__ float sh1[32 * 65];   // 32 rows, stride 65: conflict-light
    __shared__ float sh2[32 * 33];
    __shared__ float sh3[32 * 17];

    int t = threadIdx.x;
    int r = t & 31;    // local row
    int h = t >> 5;    // output half (0/1)

    for (int idx = t; idx < 128 * 64; idx += 64) sW1[idx] = W1[idx];
    for (int idx = t; idx < 64 * 32; idx += 64) sW2[idx] = W2[idx];
    for (int idx = t; idx < 32 * 16; idx += 64) sW3[idx] = W3[idx];
    for (int idx = t; idx < 16 * 16; idx += 64) sW4[idx] = W4[idx];
    sb1[t] = b1[t];
    if (t < 32) sb2[t] = b2[t];
    if (t < 16) { sb3[t] = b3[t]; sb4[t] = b4[t]; }
    __syncthreads();

    int row = blockIdx.x * 32 + r;
    const float4* xr = (const float4*)(x + (size_t)row * DIM);

    // ---- layer 1: 128 -> 64, this thread computes outputs [h*32, h*32+32) ----
    float h1[32];
    #pragma unroll
    for (int k = 0; k < 32; ++k) h1[k] = sb1[h * 32 + k];
    for (int j4 = 0; j4 < 32; ++j4) {
        float4 xv = xr[j4];
        const float* w0 = &sW1[(j4 * 4 + 0) * 64 + h * 32];
        const float* w1 = &sW1[(j4 * 4 + 1) * 64 + h * 32];
        const float* w2 = &sW1[(j4 * 4 + 2) * 64 + h * 32];
        const float* w3 = &sW1[(j4 * 4 + 3) * 64 + h * 32];
        #pragma unroll
        for (int k = 0; k < 32; ++k) h1[k] = fmaf(xv.x, w0[k], h1[k]);
        #pragma unroll
        for (int k = 0; k < 32; ++k) h1[k] = fmaf(xv.y, w1[k], h1[k]);
        #pragma unroll
        for (int k = 0; k < 32; ++k) h1[k] = fmaf(xv.z, w2[k], h1[k]);
        #pragma unroll
        for (int k = 0; k < 32; ++k) h1[k] = fmaf(xv.w, w3[k], h1[k]);
    }
    #pragma unroll
    for (int k = 0; k < 32; ++k) sh1[r * 65 + h * 32 + k] = fmaxf(h1[k], 0.0f);

    // ---- layer 2: 64 -> 32, outputs [h*16, h*16+16), inputs all 64 ----
    float h2[16];
    #pragma unroll
    for (int k = 0; k < 16; ++k) h2[k] = sb2[h * 16 + k];
    for (int j = 0; j < 64; ++j) {
        float a = sh1[r * 65 + j];
        #pragma unroll
        for (int k = 0; k < 16; ++k) h2[k] = fmaf(a, sW2[j * 32 + h * 16 + k], h2[k]);
    }
    #pragma unroll
    for (int k = 0; k < 16; ++k) sh2[r * 33 + h * 16 + k] = fmaxf(h2[k], 0.0f);

    // ---- layer 3: 32 -> 16, outputs [h*8, h*8+8) ----
    float h3[8];
    #pragma unroll
    for (int k = 0; k < 8; ++k) h3[k] = sb3[h * 8 + k];
    for (int j = 0; j < 32; ++j) {
        float a = sh2[r * 33 + j];
        #pragma unroll
        for (int k = 0; k < 8; ++k) h3[k] = fmaf(a, sW3[j * 16 + h * 8 + k], h3[k]);
    }
    #pragma unroll
    for (int k = 0; k < 8; ++k) sh3[r * 17 + h * 8 + k] = fmaxf(h3[k], 0.0f);

    // ---- layer 4: 16 -> 16, no relu, outputs [h*8, h*8+8) ----
    float zo[8];
    #pragma unroll
    for (int k = 0; k < 8; ++k) zo[k] = sb4[h * 8 + k];
    for (int j = 0; j < 16; ++j) {
        float a = sh3[r * 17 + j];
        #pragma unroll
        for (int k = 0; k < 8; ++k) zo[k] = fmaf(a, sW4[j * 16 + h * 8 + k], zo[k]);
    }

    float s = 0.0f;
    #pragma unroll
    for (int k = 0; k < 8; ++k) s = fmaf(zo[k], zo[k], s);
    s += __shfl_xor(s, 32, 64);          // combine the two halves' partial sums
    if (h == 0) sqout[row] = s;
    float4* zr = (float4*)(z + (size_t)row * 16 + h * 8);
    zr[0] = make_float4(zo[0], zo[1], zo[2], zo[3]);
    zr[1] = make_float4(zo[4], zo[5], zo[6], zo[7]);
    // transposed copy: for fixed k, 32 lanes store 32 consecutive rows
    #pragma unroll
    for (int k = 0; k < 8; ++k) zT[(size_t)(h * 8 + k) * N + row] = zo[k];
}

// ---------------------------------------------------------------------------
// Pass 1: row sums of numerator = 1/(1+dist). v4 occupancy fix (the ONLY
// change this round): NCHUNK 32 -> 64, grid (16,64) = 1024 blocks = 4
// blocks/CU = 4 waves/SIMD (was 2). R9's neutral pk-FMA result implies
// pass1 is DS-broadcast-LATENCY-bound, not issue-bound; doubling resident
// waves halves exposed latency. Total staging traffic unchanged (grid.x
// still 16); per-thread work halves; total issue work identical. Inner
// f32x2 dot + the exact max(a,0)+1 == max(a+1,1) fold kept from R9.
// ---------------------------------------------------------------------------
__global__ __launch_bounds__(256) void pass1_kernel(
    const float* __restrict__ z, const float* __restrict__ sq,
    float* __restrict__ partial)
{
    __shared__ float s_zj[JTILE * 16];
    __shared__ float s_sqj[JTILE];

    int t = threadIdx.x;
    int i0 = blockIdx.x * 256 + t;      // 0..4095
    int i1 = i0 + 4096;
    int jb = blockIdx.y * JTILE;

    // stage z tile for this block's 128-j range: thread t copies half of
    // row jb + (t>>1) (two float4s); consecutive t -> consecutive 32B chunks
    {
        int jr = t >> 1, q2 = (t & 1) * 2;
        const float4* src = (const float4*)(z + (size_t)(jb + jr) * 16);
        float4* dst = (float4*)(s_zj + jr * 16);
        dst[q2]     = src[q2];
        dst[q2 + 1] = src[q2 + 1];
        if (t < JTILE) s_sqj[t] = sq[jb + t];
    }

    f32x2 zi0[8], zi1[8];
    {
        const float4* p0 = (const float4*)(z + (size_t)i0 * 16);
        const float4* p1 = (const float4*)(z + (size_t)i1 * 16);
        #pragma unroll
        for (int q = 0; q < 4; ++q) {
            float4 v0 = p0[q]; float4 v1 = p1[q];
            zi0[2*q]   = f32x2{v0.x, v0.y}; zi0[2*q+1] = f32x2{v0.z, v0.w};
            zi1[2*q]   = f32x2{v1.x, v1.y}; zi1[2*q+1] = f32x2{v1.z, v1.w};
        }
    }
    float sqi0p = 1.0f + sq[i0], sqi1p = 1.0f + sq[i1];
    __syncthreads();

    float acc0 = 0.0f, acc1 = 0.0f;
    #pragma unroll 4
    for (int jj = 0; jj < JTILE; ++jj) {
        const float4* zj4 = (const float4*)(s_zj + jj * 16);
        f32x2 d0 = {0.0f, 0.0f}, d1 = {0.0f, 0.0f};
        #pragma unroll
        for (int q = 0; q < 4; ++q) {
            float4 v = zj4[q];                 // ds_read_b128 broadcast
            f32x2 wa = {v.x, v.y}, wb = {v.z, v.w};
            d0 += zi0[2*q] * wa;
            d0 += zi0[2*q+1] * wb;
            d1 += zi1[2*q] * wa;
            d1 += zi1[2*q+1] * wb;
        }
        float s0 = d0.x + d0.y, s1 = d1.x + d1.y;
        float sj = s_sqj[jj];
        // dist+1 = max((1+sqi)+sj - 2*dot, 1): exact (max(a,0)+1 == max(a+1,1))
        acc0 += __builtin_amdgcn_rcpf(fmaxf(fmaf(-2.0f, s0, sqi0p + sj), 1.0f));
        acc1 += __builtin_amdgcn_rcpf(fmaxf(fmaf(-2.0f, s1, sqi1p + sj), 1.0f));
    }
    partial[blockIdx.y * N + i0] = acc0;
    partial[blockIdx.y * N + i1] = acc1;
}

// ---------------------------------------------------------------------------
// Pass 2: recompute numerators, scale by 1/rowsum, stream to out.
// R3 sweep verbatim, 4 i-rows per block, grid 2048 (LOCKED: R6 measured
// 8-row at +7 us -> pass2 is HBM-store/latency-bound). Prologue reduction
// widened to the full 64-lane wave for NCHUNK=64 (no mask needed).
// ---------------------------------------------------------------------------
__global__ __launch_bounds__(256) void pass2_kernel(
    const float* __restrict__ z, const float* __restrict__ zT,
    const float* __restrict__ sq,
    const float* __restrict__ partial, float* __restrict__ out)
{
    __shared__ float s_inv[4];

    int t = threadIdx.x;
    int ibase = blockIdx.x * 4;
    int w = t >> 6, lane = t & 63;

    // rowsum: wave w reduces the NCHUNK=64 partials of row ibase+w
    {
        float v = partial[(size_t)lane * N + ibase + w];
        #pragma unroll
        for (int off = 32; off > 0; off >>= 1) v += __shfl_xor(v, off, 64);
        if (lane == 0) s_inv[w] = 1.0f / v;
    }

    float zi[4][16];
    float sqi[4];
    #pragma unroll
    for (int rr = 0; rr < 4; ++rr) {
        const float4* p = (const float4*)(z + (size_t)(ibase + rr) * 16);
        #pragma unroll
        for (int q = 0; q < 4; ++q) {
            float4 v = p[q];
            zi[rr][4*q]   = v.x; zi[rr][4*q+1] = v.y;
            zi[rr][4*q+2] = v.z; zi[rr][4*q+3] = v.w;
        }
        sqi[rr] = sq[ibase + rr];
    }
    __syncthreads();
    float inv[4];
    #pragma unroll
    for (int rr = 0; rr < 4; ++rr) inv[rr] = s_inv[rr];

    for (int jb = 0; jb < N; jb += 1024) {
        int j0 = jb + t * 4;
        // 16 contiguous 1-KB wave loads: zjT[k] = z^T[k][j0..j0+3]
        f32x4 zjT[16];
        #pragma unroll
        for (int k = 0; k < 16; ++k)
            zjT[k] = *(const f32x4*)(zT + (size_t)k * N + j0);
        f32x4 sqj = *(const f32x4*)(sq + j0);

        #pragma unroll
        for (int rr = 0; rr < 4; ++rr) {
            f32x4 d = {0.0f, 0.0f, 0.0f, 0.0f};
            #pragma unroll
            for (int k = 0; k < 16; ++k) d += zi[rr][k] * zjT[k];
            f32x4 dist = sqi[rr] + sqj - 2.0f * d;
            f32x4 num;
            num.x = __builtin_amdgcn_rcpf(1.0f + fmaxf(dist.x, 0.0f)) * inv[rr];
            num.y = __builtin_amdgcn_rcpf(1.0f + fmaxf(dist.y, 0.0f)) * inv[rr];
            num.z = __builtin_amdgcn_rcpf(1.0f + fmaxf(dist.z, 0.0f)) * inv[rr];
            num.w = __builtin_amdgcn_rcpf(1.0f + fmaxf(dist.w, 0.0f)) * inv[rr];
            __builtin_nontemporal_store(num,
                (f32x4*)(out + (size_t)(ibase + rr) * N + j0));
        }
    }
}

extern "C" void kernel_launch(void* const* d_in, const int* in_sizes, int n_in,
                              void* d_out, int out_size, void* d_ws, size_t ws_size,
                              hipStream_t stream) {
    const float* x  = (const float*)d_in[0];
    const float* W1 = (const float*)d_in[1];
    const float* b1 = (const float*)d_in[2];
    const float* W2 = (const float*)d_in[3];
    const float* b2 = (const float*)d_in[4];
    const float* W3 = (const float*)d_in[5];
    const float* b3 = (const float*)d_in[6];
    const float* W4 = (const float*)d_in[7];
    const float* b4 = (const float*)d_in[8];
    float* out = (float*)d_out;

    float* ws = (float*)d_ws;
    float* z       = ws;                        // N*16     = 131072 floats
    float* zT      = ws + N * 16;               // 16*N     = 131072 floats
    float* sqv     = ws + N * 32;               // N        =   8192 floats
    float* partial = ws + N * 32 + N;           // NCHUNK*N = 524288 floats
    // total ws usage: 794624 floats = 3.03 MiB (ws is ~1 GiB per the poison fill)

    encoder_kernel<<<256, 64, 0, stream>>>(x, W1, b1, W2, b2, W3, b3, W4, b4, z, zT, sqv);
    pass1_kernel<<<dim3(16, NCHUNK), 256, 0, stream>>>(z, sqv, partial);
    pass2_kernel<<<N / 4, 256, 0, stream>>>(z, zT, sqv, partial, out);
}